// Round 1
// baseline (453.911 us; speedup 1.0000x reference)
//
#include <hip/hip_runtime.h>
#include <math.h>

#define HID 1024
#define VOC 50257
#define MLEN 12

// K1 grid decomposition
#define K1_DOT_BLOCKS 1280        // 5120 waves: 1024 comb-half rows + 4096 hh rows
#define K1_PREF_BLOCKS 128        // prefetch 16 MB of out_W head into L2/L3
#define PREF_F4 32                // float4s per thread: 128*256*32*16B = 16 MB

// ws layout (floats)
#define WS_ATTN   0      // [1024] attn_applied
#define WS_X      1024   // [1024] relu output
#define WS_PCOMB  2048   // [1024] comb_W[:, :H] @ embedded + comb_b
#define WS_HH     3072   // [4096] W_hh @ h0 + b_ih + b_hh
#define WS_GATES  7168   // [4096]
#define WS_H      11264  // [1024] h_new (16B aligned copy)
#define WS_LSE    12288  // [1]
#define WS_CTR    12292  // uint counter for K3 last-block

__device__ __forceinline__ float wave_reduce_sum(float v) {
    for (int off = 32; off > 0; off >>= 1)
        v += __shfl_down(v, off, 64);
    return v;
}

// K1: block 0 = attention softmax + attn_applied; blocks 1..1280 = input-only GEMV
// halves (comb first-half on embedded, W_hh@h0+biases); blocks 1281+ = out_W prefetch.
__global__ __launch_bounds__(256) void k1_fused(
    const int* __restrict__ tok_p, const float* __restrict__ h0,
    const float* __restrict__ enc, const float* __restrict__ emb,
    const float* __restrict__ attn_W, const float* __restrict__ attn_b,
    const float* __restrict__ comb_W, const float* __restrict__ comb_b,
    const float* __restrict__ W_hh, const float* __restrict__ b_ih,
    const float* __restrict__ b_hh, const float* __restrict__ out_W,
    float* __restrict__ ws, float* __restrict__ out_attnw)
{
    const int t = threadIdx.x;
    const int wid = t >> 6, lane = t & 63;
    const int bid = blockIdx.x;
    const int tok = tok_p[0];  // int64 little-endian low word (tok < 50257)
    const float4* emb4 = (const float4*)(emb + (size_t)tok * HID);
    const float4* h04  = (const float4*)h0;

    if (bid == 0) {
        __shared__ float lds_logits[MLEN];
        __shared__ float lds_w[MLEN];
        if (t == 0) *((unsigned int*)(ws + WS_CTR)) = 0u;  // reset K3 counter each call
        const float4* aW4 = (const float4*)attn_W;
        for (int l = wid; l < MLEN; l += 4) {
            float s = 0.f;
            for (int k = 0; k < 8; ++k) {
                int idx = k * 64 + lane;                    // 0..511 float4s of [emb,h0]
                float4 v = (idx < 256) ? emb4[idx] : h04[idx - 256];
                float4 w = aW4[l * 512 + idx];
                s += v.x * w.x + v.y * w.y + v.z * w.z + v.w * w.w;
            }
            s = wave_reduce_sum(s);
            if (lane == 0) lds_logits[l] = s + attn_b[l];
        }
        __syncthreads();
        if (t == 0) {
            float m = -1e30f;
            for (int l = 0; l < MLEN; ++l) m = fmaxf(m, lds_logits[l]);
            float ssum = 0.f;
            for (int l = 0; l < MLEN; ++l) { float e = expf(lds_logits[l] - m); lds_w[l] = e; ssum += e; }
            float inv = 1.f / ssum;
            for (int l = 0; l < MLEN; ++l) { lds_w[l] *= inv; out_attnw[l] = lds_w[l]; }
        }
        __syncthreads();
        const float4* enc4 = (const float4*)enc;
        float4 acc = make_float4(0.f, 0.f, 0.f, 0.f);
        for (int l = 0; l < MLEN; ++l) {
            float wl = lds_w[l];
            float4 v = enc4[l * 256 + t];
            acc.x += wl * v.x; acc.y += wl * v.y; acc.z += wl * v.z; acc.w += wl * v.w;
        }
        ((float4*)(ws + WS_ATTN))[t] = acc;
    } else if (bid <= K1_DOT_BLOCKS) {
        const int gw = (bid - 1) * 4 + wid;                 // 0..5119
        float s = 0.f;
        if (gw < HID) {
            // partial_comb[gw] = comb_W[gw, :H] @ embedded + comb_b[gw]
            const float4* W4 = (const float4*)(comb_W + (size_t)gw * 2 * HID);
            for (int k = 0; k < 4; ++k) {
                int idx = k * 64 + lane;
                float4 w = W4[idx], v = emb4[idx];
                s += w.x * v.x + w.y * v.y + w.z * v.z + w.w * v.w;
            }
            s = wave_reduce_sum(s);
            if (lane == 0) ws[WS_PCOMB + gw] = s + comb_b[gw];
        } else {
            // hh_gates[r] = W_hh[r,:] @ h0 + b_ih[r] + b_hh[r]
            const int r = gw - HID;                         // 0..4095
            const float4* W4 = (const float4*)(W_hh + (size_t)r * HID);
            for (int k = 0; k < 4; ++k) {
                int idx = k * 64 + lane;
                float4 w = W4[idx], v = h04[idx];
                s += w.x * v.x + w.y * v.y + w.z * v.z + w.w * v.w;
            }
            s = wave_reduce_sum(s);
            if (lane == 0) ws[WS_HH + r] = s + b_ih[r] + b_hh[r];
        }
    } else {
        // warm L2/L3 with the head of out_W (contiguous 16 MB, coalesced)
        const int pb = bid - K1_DOT_BLOCKS - 1;             // 0..127
        const float4* W4 = (const float4*)out_W;
        const int base = pb * 256 + t;
        float acc = 0.f;
        for (int i = 0; i < PREF_F4; ++i) {
            float4 v = W4[base + i * (K1_PREF_BLOCKS * 256)];
            acc += v.x + v.y + v.z + v.w;
        }
        asm volatile("" :: "v"(acc));                      // keep loads live, no DCE
    }
}

// K2: x[r] = relu(partial_comb[r] + comb_W[r, H:] @ attn_applied); dot length 1024
__global__ __launch_bounds__(256) void k2_comb(
    const float* __restrict__ comb_W, float* __restrict__ ws)
{
    const int wid = threadIdx.x >> 6, lane = threadIdx.x & 63;
    const int row = blockIdx.x * 4 + wid;                  // 0..1023
    const float4* W4 = (const float4*)(comb_W + (size_t)row * 2 * HID + HID);
    const float4* v4 = (const float4*)(ws + WS_ATTN);
    float s = 0.f;
    for (int k = 0; k < 4; ++k) {
        int idx = k * 64 + lane;
        float4 w = W4[idx], v = v4[idx];
        s += w.x * v.x + w.y * v.y + w.z * v.z + w.w * v.w;
    }
    s = wave_reduce_sum(s);
    if (lane == 0) ws[WS_X + row] = fmaxf(s + ws[WS_PCOMB + row], 0.f);
}

// K3: gates[r] = hh_gates[r] + W_ih[r,:] @ x ; last-finishing block runs the LSTM cell
__global__ __launch_bounds__(256) void k3_gates_lstm(
    const float* __restrict__ W_ih, const float* __restrict__ c0,
    float* __restrict__ ws, float* __restrict__ out_h, float* __restrict__ out_c)
{
    const int wid = threadIdx.x >> 6, lane = threadIdx.x & 63;
    const int row = blockIdx.x * 4 + wid;                  // 0..4095
    const float4* W4 = (const float4*)(W_ih + (size_t)row * HID);
    const float4* x4 = (const float4*)(ws + WS_X);
    float s = 0.f;
    for (int k = 0; k < 4; ++k) {
        int idx = k * 64 + lane;
        float4 w = W4[idx], v = x4[idx];
        s += w.x * v.x + w.y * v.y + w.z * v.z + w.w * v.w;
    }
    s = wave_reduce_sum(s);
    if (lane == 0) ws[WS_GATES + row] = s + ws[WS_HH + row];

    // last-block fusion of the LSTM elementwise (threadFenceReduction pattern)
    __shared__ unsigned int lastflag;
    __syncthreads();                                       // all 4 waves' stores drained (vmcnt(0) before barrier)
    if (threadIdx.x == 0) {
        __threadfence();                                   // release: flush XCD L2 to coherent point
        unsigned int prev = atomicAdd((unsigned int*)(ws + WS_CTR), 1u);
        lastflag = (prev == gridDim.x - 1) ? 1u : 0u;
    }
    __syncthreads();
    if (lastflag) {
        __threadfence();                                   // acquire: invalidate stale cache
        const float* g = ws + WS_GATES;
        for (int e = threadIdx.x; e < HID; e += 256) {
            float ig = g[e];
            float fg = g[HID + e];
            float gg = g[2 * HID + e];
            float og = g[3 * HID + e];
            float i = 1.f / (1.f + expf(-ig));
            float f = 1.f / (1.f + expf(-fg));
            float o = 1.f / (1.f + expf(-og));
            float gv = tanhf(gg);
            float c = f * c0[e] + i * gv;
            float h = o * tanhf(c);
            out_c[e] = c;
            out_h[e] = h;
            ws[WS_H + e] = h;                              // aligned copy for K5
        }
    }
}

// K5: logits = out_W @ h + out_b; wave per row
__global__ __launch_bounds__(256) void k5_logits(
    const float* __restrict__ ws, const float* __restrict__ out_W,
    const float* __restrict__ out_b, float* __restrict__ out_logp)
{
    const int wid = threadIdx.x >> 6, lane = threadIdx.x & 63;
    const int row = blockIdx.x * 4 + wid;
    if (row >= VOC) return;
    const float4* W4 = (const float4*)(out_W + (size_t)row * HID);
    const float4* h4 = (const float4*)(ws + WS_H);
    float s = 0.f;
    for (int k = 0; k < 4; ++k) {
        int idx = k * 64 + lane;
        float4 w = W4[idx], h = h4[idx];
        s += w.x * h.x + w.y * h.y + w.z * h.z + w.w * h.w;
    }
    s = wave_reduce_sum(s);
    if (lane == 0) out_logp[row] = s + out_b[row];
}

// K6: single-block log-sum-exp over the 50257 logits (L2-resident, two passes)
__global__ __launch_bounds__(1024) void k6_lse(
    const float* __restrict__ logits, float* __restrict__ ws)
{
    __shared__ float red[16];
    __shared__ float red2[16];
    const int t = threadIdx.x;
    const int wid = t >> 6, lane = t & 63;
    float m = -1e30f;
    for (int i = t; i < VOC; i += 1024) m = fmaxf(m, logits[i]);
    for (int off = 32; off > 0; off >>= 1) m = fmaxf(m, __shfl_xor(m, off, 64));
    if (lane == 0) red[wid] = m;
    __syncthreads();
    if (t == 0) {
        float mm = red[0];
        for (int w = 1; w < 16; ++w) mm = fmaxf(mm, red[w]);
        red[0] = mm;
    }
    __syncthreads();
    m = red[0];
    float s = 0.f;
    for (int i = t; i < VOC; i += 1024) s += expf(logits[i] - m);
    s = wave_reduce_sum(s);
    if (lane == 0) red2[wid] = s;
    __syncthreads();
    if (t == 0) {
        float ss = 0.f;
        for (int w = 0; w < 16; ++w) ss += red2[w];
        ws[WS_LSE] = m + logf(ss);
    }
}

// K7: logp = logits - lse (in place)
__global__ __launch_bounds__(256) void k7_sub(
    float* __restrict__ out_logp, const float* __restrict__ ws)
{
    const int i = blockIdx.x * 256 + threadIdx.x;
    if (i < VOC) out_logp[i] -= ws[WS_LSE];
}

extern "C" void kernel_launch(void* const* d_in, const int* in_sizes, int n_in,
                              void* d_out, int out_size, void* d_ws, size_t ws_size,
                              hipStream_t stream) {
    const int*   tok      = (const int*)d_in[0];
    const float* h_hidden = (const float*)d_in[1];
    const float* c_hidden = (const float*)d_in[2];
    const float* enc      = (const float*)d_in[3];
    const float* emb      = (const float*)d_in[4];
    const float* attn_W   = (const float*)d_in[5];
    const float* attn_b   = (const float*)d_in[6];
    const float* comb_W   = (const float*)d_in[7];
    const float* comb_b   = (const float*)d_in[8];
    const float* W_ih     = (const float*)d_in[9];
    const float* W_hh     = (const float*)d_in[10];
    const float* b_ih     = (const float*)d_in[11];
    const float* b_hh     = (const float*)d_in[12];
    const float* out_W    = (const float*)d_in[13];
    const float* out_b    = (const float*)d_in[14];

    float* out       = (float*)d_out;
    float* out_logp  = out;                       // [50257]
    float* out_h     = out + VOC;                 // [1024]
    float* out_c     = out + VOC + HID;           // [1024]
    float* out_attnw = out + VOC + 2 * HID;       // [12]

    float* ws = (float*)d_ws;

    k1_fused<<<1 + K1_DOT_BLOCKS + K1_PREF_BLOCKS, 256, 0, stream>>>(
        tok, h_hidden, enc, emb, attn_W, attn_b, comb_W, comb_b,
        W_hh, b_ih, b_hh, out_W, ws, out_attnw);
    k2_comb<<<HID / 4, 256, 0, stream>>>(comb_W, ws);
    k3_gates_lstm<<<4 * HID / 4, 256, 0, stream>>>(W_ih, c_hidden, ws, out_h, out_c);
    k5_logits<<<(VOC + 3) / 4, 256, 0, stream>>>(ws, out_W, out_b, out_logp);
    k6_lse<<<1, 1024, 0, stream>>>(out_logp, ws);
    k7_sub<<<(VOC + 255) / 256, 256, 0, stream>>>(out_logp, ws);
}